// Round 1
// baseline (279.949 us; speedup 1.0000x reference)
//
#include <hip/hip_runtime.h>

// Guided filter, R=1 (3x3 box), EPS=0.01, shape (8,3,1024,1024) fp32.
// Fused single kernel: 32x32 output tile per 256-thread block.
//   LDS: 36x36 halo tile of x,y  ->  34x34 tile of A,b  ->  32x32 outputs.
// box(x)/Nrm simplifies to sum/count with count = cnt_row*cnt_col
// (2 at image borders, 3 interior), applied as an exact multiply:
// 0.5 or 1/3 per axis (0.5*0.5, 0.5*(1/3), (1/3)^2 match 1/4, 1/6, ~1/9).

#define H 1024
#define W 1024
#define TILE 32

__global__ __launch_bounds__(256) void guided_filter_kernel(
    const float* __restrict__ x, const float* __restrict__ y,
    float* __restrict__ out)
{
    __shared__ float sx[36][37];   // +1 pad: odd stride, no 2^k bank aliasing
    __shared__ float sy[36][37];
    __shared__ float sA[34][35];
    __shared__ float sB[34][35];

    const int tid = threadIdx.x;
    const int gx0 = blockIdx.x * TILE;
    const int gy0 = blockIdx.y * TILE;
    const long base = (long)blockIdx.z * (long)(H * W);
    const float* __restrict__ xp = x + base;
    const float* __restrict__ yp = y + base;
    float* __restrict__ op = out + base;

    // ---- stage 0: load 36x36 halo tile of x and y (zero pad outside image)
    for (int idx = tid; idx < 36 * 36; idx += 256) {
        const int li = idx / 36;
        const int lj = idx - li * 36;
        const int gi = gy0 - 2 + li;
        const int gj = gx0 - 2 + lj;
        float xv = 0.0f, yv = 0.0f;
        if ((unsigned)gi < (unsigned)H && (unsigned)gj < (unsigned)W) {
            const int o = gi * W + gj;
            xv = xp[o];
            yv = yp[o];
        }
        sx[li][lj] = xv;
        sy[li][lj] = yv;
    }
    __syncthreads();

    const float third = 1.0f / 3.0f;

    // ---- stage 1: A,b on the 34x34 region (output tile + 1 ring)
    for (int idx = tid; idx < 34 * 34; idx += 256) {
        const int ai = idx / 34;
        const int aj = idx - ai * 34;
        const int gi = gy0 - 1 + ai;
        const int gj = gx0 - 1 + aj;
        float Av = 0.0f, Bv = 0.0f;
        if ((unsigned)gi < (unsigned)H && (unsigned)gj < (unsigned)W) {
            float sxs = 0.0f, sys = 0.0f, sxx = 0.0f, sxy = 0.0f;
#pragma unroll
            for (int di = 0; di < 3; ++di) {
#pragma unroll
                for (int dj = 0; dj < 3; ++dj) {
                    const float xv = sx[ai + di][aj + dj];
                    const float yv = sy[ai + di][aj + dj];
                    sxs += xv;
                    sys += yv;
                    sxx = fmaf(xv, xv, sxx);
                    sxy = fmaf(xv, yv, sxy);
                }
            }
            const float invr = (gi == 0 || gi == H - 1) ? 0.5f : third;
            const float invc = (gj == 0 || gj == W - 1) ? 0.5f : third;
            const float inv  = invr * invc;
            const float mx = sxs * inv;
            const float my = sys * inv;
            const float cov = fmaf(-mx, my, sxy * inv);
            const float var = fmaf(-mx, mx, sxx * inv);
            Av = cov / (var + 0.01f);
            Bv = fmaf(-Av, mx, my);
        }
        sA[ai][aj] = Av;
        sB[ai][aj] = Bv;
    }
    __syncthreads();

    // ---- stage 2: 3x3 box of A,b + final fma, 32x32 outputs
    const int tx = tid & 31;
    const int ty = tid >> 5;   // 0..7
#pragma unroll
    for (int r = 0; r < 4; ++r) {
        const int oi = ty + 8 * r;
        const int oj = tx;
        const int gi = gy0 + oi;   // always in [0,H) since 1024 % 32 == 0
        const int gj = gx0 + oj;
        float sA9 = 0.0f, sB9 = 0.0f;
#pragma unroll
        for (int di = 0; di < 3; ++di) {
#pragma unroll
            for (int dj = 0; dj < 3; ++dj) {
                sA9 += sA[oi + di][oj + dj];
                sB9 += sB[oi + di][oj + dj];
            }
        }
        const float invr = (gi == 0 || gi == H - 1) ? 0.5f : third;
        const float invc = (gj == 0 || gj == W - 1) ? 0.5f : third;
        const float inv  = invr * invc;
        const float mA = sA9 * inv;
        const float mB = sB9 * inv;
        op[gi * W + gj] = fmaf(mA, sx[oi + 2][oj + 2], mB);
    }
}

extern "C" void kernel_launch(void* const* d_in, const int* in_sizes, int n_in,
                              void* d_out, int out_size, void* d_ws, size_t ws_size,
                              hipStream_t stream) {
    const float* x = (const float*)d_in[0];
    const float* y = (const float*)d_in[1];
    float* out = (float*)d_out;
    const int planes = in_sizes[0] / (H * W);   // N*C = 24
    dim3 grid(W / TILE, H / TILE, planes);
    guided_filter_kernel<<<grid, dim3(256), 0, stream>>>(x, y, out);
}

// Round 2
// 263.166 us; speedup vs baseline: 1.0638x; 1.0638x over previous
//
#include <hip/hip_runtime.h>

// Guided filter r=1, eps=0.01, (8,3,1024,1024) fp32 — register-streaming version.
// No LDS. Each wave owns a 128-col x 32-row strip (2 cols/lane).
// Per row step: load x,y (float2), 3-tap horizontal sums via __shfl (+ edge-lane
// halo column pipeline), rotating 3-row register windows: h-sums -> A,b -> hA,hb
// -> output. box()/Nrm == sum/count; count applied as exact 0.5 / (1/3) factors.
// Halo-col A,b forced to 0 outside image via invcH=0 (matches zero padding).

#define H 1024
#define W 1024
#define STRIP 32      // output rows per wave
#define WAVES 4       // waves per block (stacked vertically)
#define WVC 128       // columns per wave (2 per lane)

__global__ __launch_bounds__(256, 4) void gf_kernel(const float* __restrict__ xg,
                                                    const float* __restrict__ yg,
                                                    float* __restrict__ og)
{
    const int lane = threadIdx.x & 63;
    const int wv = threadIdx.x >> 6;
    const int c0 = blockIdx.x * WVC;
    const int R0 = (blockIdx.y * WAVES + wv) * STRIP;
    const size_t base = (size_t)blockIdx.z * (size_t)(H * W);
    const float* __restrict__ xp = xg + base;
    const float* __restrict__ yp = yg + base;
    float* __restrict__ op = og + base;

    const int colA = c0 + 2 * lane;            // first of this lane's 2 columns
    const bool isL = (lane == 0);
    const bool isR = (lane == 63);
    // halo: lane 0 computes A,b for col c0-1 (needs cols c0-2,c0-1);
    //       lane 63 computes A,b for col c0+128 (needs cols c0+128,c0+129).
    const bool haloIn = isL ? (c0 > 0) : (isR ? (c0 + WVC < W) : false);
    const int hdelta = (isL ? (c0 - 2) : (c0 + WVC)) - colA;

    const float third = 1.0f / 3.0f;
    const float invcA = (colA == 0) ? 0.5f : third;          // colA even, never W-1
    const float invcB = (colA + 1 == W - 1) ? 0.5f : third;  // colB odd, never 0
    const float invcH = haloIn ? third : 0.0f;               // kills out-of-image halo A,b

    // rotating 3-row windows (all registers)
    float hxA[3]={0,0,0}, hxB[3]={0,0,0}, hyA[3]={0,0,0}, hyB[3]={0,0,0};
    float hxxA[3]={0,0,0}, hxxB[3]={0,0,0}, hxyA[3]={0,0,0}, hxyB[3]={0,0,0};
    float hxH[3]={0,0,0}, hyH[3]={0,0,0}, hxxH[3]={0,0,0}, hxyH[3]={0,0,0};
    float hAA[3]={0,0,0}, hAB[3]={0,0,0}, hbA[3]={0,0,0}, hbB[3]={0,0,0};
    float xwA[3]={0,0,0}, xwB[3]={0,0,0};

    int off = (R0 - 2) * W + colA;

    // prime: load row R0-2 (zero if above image)
    float2 xv = {0,0}, yv = {0,0}, xh = {0,0}, yh = {0,0};
    if (R0 - 2 >= 0) {
        xv = *(const float2*)(xp + off);
        yv = *(const float2*)(yp + off);
        if (haloIn) {
            xh = *(const float2*)(xp + off + hdelta);
            yh = *(const float2*)(yp + off + hdelta);
        }
    }

#pragma unroll 3
    for (int s = 0; s < STRIP + 4; ++s) {
        const int lr = R0 - 2 + s;   // row held in xv/yv
        const int t = lr - 1;        // A,b row produced this step
        const int r = lr - 2;        // output row produced this step

        // ---- prefetch next row (hides load latency behind this step's math)
        const int lrn = lr + 1;
        float2 xvN = {0,0}, yvN = {0,0}, xhN = {0,0}, yhN = {0,0};
        if (lrn >= 0 && lrn < H && s < STRIP + 3) {
            const int offn = off + W;
            xvN = *(const float2*)(xp + offn);
            yvN = *(const float2*)(yp + offn);
            if (haloIn) {
                xhN = *(const float2*)(xp + offn + hdelta);
                yhN = *(const float2*)(yp + offn + hdelta);
            }
        }

        // ---- products + horizontal neighbor exchange for row lr
        const float xxA = xv.x * xv.x, xxB = xv.y * xv.y;
        const float xyA = xv.x * yv.x, xyB = xv.y * yv.y;
        float xl = __shfl_up(xv.y, 1, 64);
        float xr = __shfl_down(xv.x, 1, 64);
        float yl = __shfl_up(yv.y, 1, 64);
        float yr = __shfl_down(yv.x, 1, 64);
        xl = isL ? xh.y : xl;
        xr = isR ? xh.x : xr;
        yl = isL ? yh.y : yl;
        yr = isR ? yh.x : yr;

        // shift stage-1 windows
        hxA[0]=hxA[1]; hxA[1]=hxA[2];   hxB[0]=hxB[1]; hxB[1]=hxB[2];
        hyA[0]=hyA[1]; hyA[1]=hyA[2];   hyB[0]=hyB[1]; hyB[1]=hyB[2];
        hxxA[0]=hxxA[1]; hxxA[1]=hxxA[2]; hxxB[0]=hxxB[1]; hxxB[1]=hxxB[2];
        hxyA[0]=hxyA[1]; hxyA[1]=hxyA[2]; hxyB[0]=hxyB[1]; hxyB[1]=hxyB[2];
        hxH[0]=hxH[1]; hxH[1]=hxH[2];   hyH[0]=hyH[1]; hyH[1]=hyH[2];
        hxxH[0]=hxxH[1]; hxxH[1]=hxxH[2]; hxyH[0]=hxyH[1]; hxyH[1]=hxyH[2];

        // 3-tap horizontal sums for the lane's two columns (shared middle term)
        const float sx = xv.x + xv.y;
        hxA[2] = xl + sx;   hxB[2] = sx + xr;
        const float sy = yv.x + yv.y;
        hyA[2] = yl + sy;   hyB[2] = sy + yr;
        const float sxx = xxA + xxB;
        hxxA[2] = fmaf(xl, xl, sxx);  hxxB[2] = fmaf(xr, xr, sxx);
        const float sxy = xyA + xyB;
        hxyA[2] = fmaf(xl, yl, sxy);  hxyB[2] = fmaf(xr, yr, sxy);

        // halo column h-sums (same code path for lane 0 / lane 63; others garbage, unused)
        const float selx  = isL ? xv.x : xv.y;
        const float sely  = isL ? yv.x : yv.y;
        const float selxx = isL ? xxA : xxB;
        const float selxy = isL ? xyA : xyB;
        hxH[2]  = xh.x + xh.y + selx;
        hyH[2]  = yh.x + yh.y + sely;
        hxxH[2] = fmaf(xh.x, xh.x, fmaf(xh.y, xh.y, selxx));
        hxyH[2] = fmaf(xh.x, yh.x, fmaf(xh.y, yh.y, selxy));

        // ---- stage 1: A,b for row t (rowfA=0 outside image zeroes everything)
        const float rowfA = (t < 0 || t >= H) ? 0.0f
                          : ((t == 0 || t == H - 1) ? 0.5f : third);
        const float iA = rowfA * invcA;
        const float iB = rowfA * invcB;
        const float iH = rowfA * invcH;

        float AcA, bcA, AcB, bcB, Ah, bh;
        {
            const float mx  = (hxA[0] + hxA[1] + hxA[2]) * iA;
            const float my  = (hyA[0] + hyA[1] + hyA[2]) * iA;
            const float mxx = (hxxA[0] + hxxA[1] + hxxA[2]) * iA;
            const float mxy = (hxyA[0] + hxyA[1] + hxyA[2]) * iA;
            const float var = fmaf(-mx, mx, mxx);
            const float cov = fmaf(-mx, my, mxy);
            AcA = cov * __builtin_amdgcn_rcpf(var + 0.01f);
            bcA = fmaf(-AcA, mx, my);
        }
        {
            const float mx  = (hxB[0] + hxB[1] + hxB[2]) * iB;
            const float my  = (hyB[0] + hyB[1] + hyB[2]) * iB;
            const float mxx = (hxxB[0] + hxxB[1] + hxxB[2]) * iB;
            const float mxy = (hxyB[0] + hxyB[1] + hxyB[2]) * iB;
            const float var = fmaf(-mx, mx, mxx);
            const float cov = fmaf(-mx, my, mxy);
            AcB = cov * __builtin_amdgcn_rcpf(var + 0.01f);
            bcB = fmaf(-AcB, mx, my);
        }
        {
            const float mx  = (hxH[0] + hxH[1] + hxH[2]) * iH;
            const float my  = (hyH[0] + hyH[1] + hyH[2]) * iH;
            const float mxx = (hxxH[0] + hxxH[1] + hxxH[2]) * iH;
            const float mxy = (hxyH[0] + hxyH[1] + hxyH[2]) * iH;
            const float var = fmaf(-mx, mx, mxx);
            const float cov = fmaf(-mx, my, mxy);
            Ah = cov * __builtin_amdgcn_rcpf(var + 0.01f);
            bh = fmaf(-Ah, mx, my);
        }

        // ---- stage 2: horizontal 3-sums of A,b for row t
        float Al = __shfl_up(AcB, 1, 64);
        float Ar = __shfl_down(AcA, 1, 64);
        float bl = __shfl_up(bcB, 1, 64);
        float br = __shfl_down(bcA, 1, 64);
        Al = isL ? Ah : Al;   Ar = isR ? Ah : Ar;
        bl = isL ? bh : bl;   br = isR ? bh : br;

        hAA[0]=hAA[1]; hAA[1]=hAA[2];  hAB[0]=hAB[1]; hAB[1]=hAB[2];
        hbA[0]=hbA[1]; hbA[1]=hbA[2];  hbB[0]=hbB[1]; hbB[1]=hbB[2];
        const float sA = AcA + AcB;
        hAA[2] = Al + sA;  hAB[2] = sA + Ar;
        const float sb = bcA + bcB;
        hbA[2] = bl + sb;  hbB[2] = sb + br;

        xwA[0]=xwA[1]; xwA[1]=xwA[2]; xwA[2]=xv.x;
        xwB[0]=xwB[1]; xwB[1]=xwB[2]; xwB[2]=xv.y;

        // ---- output row r
        if (s >= 4) {
            const float rowfO = (r == 0 || r == H - 1) ? 0.5f : third;
            const float oA = rowfO * invcA;
            const float oB = rowfO * invcB;
            float2 o;
            o.x = fmaf((hAA[0] + hAA[1] + hAA[2]) * oA, xwA[0],
                       (hbA[0] + hbA[1] + hbA[2]) * oA);
            o.y = fmaf((hAB[0] + hAB[1] + hAB[2]) * oB, xwB[0],
                       (hbB[0] + hbB[1] + hbB[2]) * oB);
            *(float2*)(op + (off - 2 * W)) = o;
        }

        // rotate prefetched row in
        xv = xvN; yv = yvN; xh = xhN; yh = yhN;
        off += W;
    }
}

extern "C" void kernel_launch(void* const* d_in, const int* in_sizes, int n_in,
                              void* d_out, int out_size, void* d_ws, size_t ws_size,
                              hipStream_t stream) {
    const float* x = (const float*)d_in[0];
    const float* y = (const float*)d_in[1];
    float* out = (float*)d_out;
    const int planes = in_sizes[0] / (H * W);              // N*C = 24
    dim3 grid(W / WVC, H / (STRIP * WAVES), planes);       // 8 x 8 x 24 = 1536 blocks
    gf_kernel<<<grid, dim3(256), 0, stream>>>(x, y, out);
}

// Round 3
// 253.813 us; speedup vs baseline: 1.1030x; 1.0369x over previous
//
#include <hip/hip_runtime.h>

// Guided filter r=1, eps=0.01, (8,3,1024,1024) fp32.
// Register-streaming v2: vertical-sums-first, 4 cols/lane (float4), 2-register
// sliding vertical windows (p = prev2+prev1, r = prev1; v = p + new), single
// dependent shuffle stage per box pass (shuffle the vertical sums).
// Wave strip: 256 cols x 16 rows. Edge lanes maintain a 2-col halo pipeline.
// box()/Nrm == sum/count; count applied as exact 0.5 / (1/3) row x col factors.

#define H 1024
#define W 1024
#define STRIP 16      // output rows per wave
#define WAVES 4       // waves per block (stacked vertically)
#define WVC 256       // columns per wave (4 per lane)

__global__ __launch_bounds__(256, 3) void gf_kernel(const float* __restrict__ xg,
                                                    const float* __restrict__ yg,
                                                    float* __restrict__ og)
{
    const int lane = threadIdx.x & 63;
    const int wv = threadIdx.x >> 6;
    const int c0 = blockIdx.x * WVC;
    const int R0 = (blockIdx.y * WAVES + wv) * STRIP;
    const size_t base = (size_t)blockIdx.z * (size_t)(H * W);
    const float* __restrict__ xp = xg + base;
    const float* __restrict__ yp = yg + base;
    float* __restrict__ op = og + base;

    const int colA = c0 + 4 * lane;          // first of this lane's 4 columns
    const bool isL = (lane == 0);
    const bool isR = (lane == 63);
    // lane0 halo cols: c0-2 (h0), c0-1 (h1).  lane63: c0+256 (h0), c0+257 (h1).
    const bool haloIn = isL ? (c0 > 0) : (isR ? (c0 + WVC < W) : false);
    const int hoff = (isL ? (c0 - 2) : (c0 + WVC)) - colA;

    const float third = 1.0f / 3.0f;
    float invc[4];
    invc[0] = (colA == 0) ? 0.5f : third;        // col%4==0 -> only col 0 possible edge
    invc[1] = third;
    invc[2] = third;
    invc[3] = (colA + 3 == W - 1) ? 0.5f : third;
    const float invcH = haloIn ? third : 0.0f;   // halo col always interior when valid

    // sliding vertical state: v(new) = p + new; p' = r + new; r' = new
    float pX[4] = {0,0,0,0}, rX[4] = {0,0,0,0};
    float pY[4] = {0,0,0,0}, rY[4] = {0,0,0,0};
    float pXX[4] = {0,0,0,0}, rXX[4] = {0,0,0,0};
    float pXY[4] = {0,0,0,0}, rXY[4] = {0,0,0,0};
    float pHX[2] = {0,0}, rHX[2] = {0,0};
    float pHY[2] = {0,0}, rHY[2] = {0,0};
    float pHXX[2] = {0,0}, rHXX[2] = {0,0};
    float pHXY[2] = {0,0}, rHXY[2] = {0,0};
    float pA[4] = {0,0,0,0}, rA[4] = {0,0,0,0};
    float pB[4] = {0,0,0,0}, rB[4] = {0,0,0,0};
    float pAH = 0, rAH = 0, pBH = 0, rBH = 0;

    int off = (R0 - 2) * W + colA;

    // prime: row R0-2 (zeros above image)
    float4 xv = {0,0,0,0}, yv = {0,0,0,0};
    float2 xh = {0,0}, yh = {0,0};
    if (R0 - 2 >= 0) {
        xv = *(const float4*)(xp + off);
        yv = *(const float4*)(yp + off);
        if (haloIn) {
            xh = *(const float2*)(xp + off + hoff);
            yh = *(const float2*)(yp + off + hoff);
        }
    }

#pragma unroll 2
    for (int s = 0; s < STRIP + 4; ++s) {
        const int lr = R0 - 2 + s;   // row held in xv/yv
        const int t = lr - 1;        // A,b row produced this step
        const int r = lr - 2;        // output row produced this step

        // ---- prefetch next row (decouples load latency by one iteration)
        const int lrn = lr + 1;
        float4 xvN = {0,0,0,0}, yvN = {0,0,0,0};
        float2 xhN = {0,0}, yhN = {0,0};
        if ((unsigned)lrn < (unsigned)H && s < STRIP + 3) {
            const int offn = off + W;
            xvN = *(const float4*)(xp + offn);
            yvN = *(const float4*)(yp + offn);
            if (haloIn) {
                xhN = *(const float2*)(xp + offn + hoff);
                yhN = *(const float2*)(yp + offn + hoff);
            }
        }

        // ---- products + vertical window update (own 4 cols)
        const float x_[4] = {xv.x, xv.y, xv.z, xv.w};
        const float y_[4] = {yv.x, yv.y, yv.z, yv.w};
        float vX[4], vY[4], vXX[4], vXY[4];
#pragma unroll
        for (int c = 0; c < 4; ++c) {
            const float xx = x_[c] * x_[c];
            const float xy = x_[c] * y_[c];
            vX[c]  = pX[c]  + x_[c]; pX[c]  = rX[c]  + x_[c]; rX[c]  = x_[c];
            vY[c]  = pY[c]  + y_[c]; pY[c]  = rY[c]  + y_[c]; rY[c]  = y_[c];
            vXX[c] = pXX[c] + xx;    pXX[c] = rXX[c] + xx;    rXX[c] = xx;
            vXY[c] = pXY[c] + xy;    pXY[c] = rXY[c] + xy;    rXY[c] = xy;
        }
        // halo cols (meaningful only on edge lanes; zeros elsewhere)
        const float xh_[2] = {xh.x, xh.y};
        const float yh_[2] = {yh.x, yh.y};
        float vHX[2], vHY[2], vHXX[2], vHXY[2];
#pragma unroll
        for (int c = 0; c < 2; ++c) {
            const float xx = xh_[c] * xh_[c];
            const float xy = xh_[c] * yh_[c];
            vHX[c]  = pHX[c]  + xh_[c]; pHX[c]  = rHX[c]  + xh_[c]; rHX[c]  = xh_[c];
            vHY[c]  = pHY[c]  + yh_[c]; pHY[c]  = rHY[c]  + yh_[c]; rHY[c]  = yh_[c];
            vHXX[c] = pHXX[c] + xx;     pHXX[c] = rHXX[c] + xx;     rHXX[c] = xx;
            vHXY[c] = pHXY[c] + xy;     pHXY[c] = rHXY[c] + xy;     rHXY[c] = xy;
        }

        // ---- single shuffle stage on vertical sums
        float lX  = __shfl_up(vX[3], 1, 64),  rXs  = __shfl_down(vX[0], 1, 64);
        float lY  = __shfl_up(vY[3], 1, 64),  rYs  = __shfl_down(vY[0], 1, 64);
        float lXX = __shfl_up(vXX[3], 1, 64), rXXs = __shfl_down(vXX[0], 1, 64);
        float lXY = __shfl_up(vXY[3], 1, 64), rXYs = __shfl_down(vXY[0], 1, 64);
        lX  = isL ? vHX[1]  : lX;   rXs  = isR ? vHX[0]  : rXs;
        lY  = isL ? vHY[1]  : lY;   rYs  = isR ? vHY[0]  : rYs;
        lXX = isL ? vHXX[1] : lXX;  rXXs = isR ? vHXX[0] : rXXs;
        lXY = isL ? vHXY[1] : lXY;  rXYs = isR ? vHXY[0] : rXYs;

        // ---- horizontal 3-sums (pair-sum trick)
        float hX[4], hY[4], hXX[4], hXY[4];
        {
            const float s01 = vX[0] + vX[1], s12 = vX[1] + vX[2], s23 = vX[2] + vX[3];
            hX[0] = lX + s01; hX[1] = s01 + vX[2]; hX[2] = s12 + vX[3]; hX[3] = s23 + rXs;
        }
        {
            const float s01 = vY[0] + vY[1], s12 = vY[1] + vY[2], s23 = vY[2] + vY[3];
            hY[0] = lY + s01; hY[1] = s01 + vY[2]; hY[2] = s12 + vY[3]; hY[3] = s23 + rYs;
        }
        {
            const float s01 = vXX[0] + vXX[1], s12 = vXX[1] + vXX[2], s23 = vXX[2] + vXX[3];
            hXX[0] = lXX + s01; hXX[1] = s01 + vXX[2]; hXX[2] = s12 + vXX[3]; hXX[3] = s23 + rXXs;
        }
        {
            const float s01 = vXY[0] + vXY[1], s12 = vXY[1] + vXY[2], s23 = vXY[2] + vXY[3];
            hXY[0] = lXY + s01; hXY[1] = s01 + vXY[2]; hXY[2] = s12 + vXY[3]; hXY[3] = s23 + rXYs;
        }

        // ---- stage 1: A,b for row t (rowfA=0 outside image zeroes everything)
        const float rowfA = ((unsigned)t >= (unsigned)H) ? 0.0f
                          : ((t == 0 || t == H - 1) ? 0.5f : third);
        float A_[4], B_[4];
#pragma unroll
        for (int c = 0; c < 4; ++c) {
            const float ic  = rowfA * invc[c];
            const float mx  = hX[c]  * ic;
            const float my  = hY[c]  * ic;
            const float mxx = hXX[c] * ic;
            const float mxy = hXY[c] * ic;
            const float var = fmaf(-mx, mx, mxx);
            const float cov = fmaf(-mx, my, mxy);
            A_[c] = cov * __builtin_amdgcn_rcpf(var + 0.01f);
            B_[c] = fmaf(-A_[c], mx, my);
        }
        // halo-column A,b (one per edge lane; garbage-but-finite elsewhere)
        float AH, BH;
        {
            const float iH  = rowfA * invcH;
            const float hx  = vHX[0]  + vHX[1]  + (isL ? vX[0]  : vX[3]);
            const float hy  = vHY[0]  + vHY[1]  + (isL ? vY[0]  : vY[3]);
            const float hxx = vHXX[0] + vHXX[1] + (isL ? vXX[0] : vXX[3]);
            const float hxy = vHXY[0] + vHXY[1] + (isL ? vXY[0] : vXY[3]);
            const float mx  = hx * iH, my = hy * iH, mxx = hxx * iH, mxy = hxy * iH;
            const float var = fmaf(-mx, mx, mxx);
            const float cov = fmaf(-mx, my, mxy);
            AH = cov * __builtin_amdgcn_rcpf(var + 0.01f);
            BH = fmaf(-AH, mx, my);
        }

        // ---- A,b vertical windows
        float vA[4], vB[4];
#pragma unroll
        for (int c = 0; c < 4; ++c) {
            vA[c] = pA[c] + A_[c]; pA[c] = rA[c] + A_[c]; rA[c] = A_[c];
            vB[c] = pB[c] + B_[c]; pB[c] = rB[c] + B_[c]; rB[c] = B_[c];
        }
        const float vAH = pAH + AH;  pAH = rAH + AH;  rAH = AH;
        const float vBH = pBH + BH;  pBH = rBH + BH;  rBH = BH;

        // ---- shuffle stage on A,b vertical sums
        float lA = __shfl_up(vA[3], 1, 64), rAs = __shfl_down(vA[0], 1, 64);
        float lB = __shfl_up(vB[3], 1, 64), rBs = __shfl_down(vB[0], 1, 64);
        lA = isL ? vAH : lA;  rAs = isR ? vAH : rAs;
        lB = isL ? vBH : lB;  rBs = isR ? vBH : rBs;

        // ---- output row r
        if (s >= 4) {
            float hA[4], hB[4];
            {
                const float s01 = vA[0] + vA[1], s12 = vA[1] + vA[2], s23 = vA[2] + vA[3];
                hA[0] = lA + s01; hA[1] = s01 + vA[2]; hA[2] = s12 + vA[3]; hA[3] = s23 + rAs;
            }
            {
                const float s01 = vB[0] + vB[1], s12 = vB[1] + vB[2], s23 = vB[2] + vB[3];
                hB[0] = lB + s01; hB[1] = s01 + vB[2]; hB[2] = s12 + vB[3]; hB[3] = s23 + rBs;
            }
            const float rowfO = (r == 0 || r == H - 1) ? 0.5f : third;
            float4 o;
            float o_[4];
#pragma unroll
            for (int c = 0; c < 4; ++c) {
                const float oc = rowfO * invc[c];
                const float xc = vX[c] - pX[c];     // = x at row r (post-update identity)
                o_[c] = fmaf(hA[c] * oc, xc, hB[c] * oc);
            }
            o.x = o_[0]; o.y = o_[1]; o.z = o_[2]; o.w = o_[3];
            *(float4*)(op + (off - 2 * W)) = o;
        }

        // rotate prefetched row in (renamed by unroll-2, no movs)
        xv = xvN; yv = yvN; xh = xhN; yh = yhN;
        off += W;
    }
}

extern "C" void kernel_launch(void* const* d_in, const int* in_sizes, int n_in,
                              void* d_out, int out_size, void* d_ws, size_t ws_size,
                              hipStream_t stream) {
    const float* x = (const float*)d_in[0];
    const float* y = (const float*)d_in[1];
    float* out = (float*)d_out;
    const int planes = in_sizes[0] / (H * W);                  // N*C = 24
    dim3 grid(W / WVC, H / (STRIP * WAVES), planes);           // 4 x 16 x 24 = 1536
    gf_kernel<<<grid, dim3(256), 0, stream>>>(x, y, out);
}